// Round 5
// baseline (407.161 us; speedup 1.0000x reference)
//
#include <hip/hip_runtime.h>
#include <hip/hip_bf16.h>
#include <math.h>

// MultiHash R11: restructure to break the reg/LDS occupancy coupling.
// R10 post-mortem: pair-load gathers (-25% line transactions) = FLAT, VALU
// up, conflicts up -> the limiter is exposed gather LATENCY x too few waves
// (10/CU), not L1 line throughput. R7/R9 showed the 128-reg/4-wave cap
// spills with the both-halves-preload structure (32 VGPR held) and
// un-aliasing LDS costs 19456 B (8 blocks/CU). So: process ONE 32-sample
// half end-to-end per outer iteration, encode split 2-lanes-per-sample
// (lanes 0-31: levels 0-7; lanes 32-63: levels 8-15 of the SAME samples):
//   - sF = [32][40] hi+lo = 5120 B; sA = 9216 B aliases it -> LDS 9216 B.
//   - no cross-half preload: a1 frags transient -> peak ~90 unified regs
//     -> (64,4) fits WITHOUT spill -> 16 waves/CU (was 10).
//   - total gathers/VALU/MFMA identical to R8; only the lane->(sample,
//     level) mapping changed; all transposes still via same-wave in-order
//     LDS (no barriers, single-wave block).
// res.r selected via compile-time-indexed ternary (rule #20: divergent
// array index would go to scratch).
// Spill gate: WRITE_SIZE must stay ~12.3 MB.
// Unchanged: weight-split prepass, split-bf16 MFMA, fragment layouts,
// epilogues (R6-validated; absmax 1.49e-8 vs 8.9e-8 threshold).

#define TBL_MASK 16383u
#define PRIME1   2654435761u

typedef __attribute__((ext_vector_type(8))) short short8;
typedef __attribute__((ext_vector_type(4))) float f32x4;
typedef __attribute__((ext_vector_type(4))) unsigned int uint4v;

struct ResArr { float r[16]; };

__device__ __forceinline__ unsigned short bf16rn(float f) {
    __hip_bfloat16 h = __float2bfloat16(f);   // RNE
    return __builtin_bit_cast(unsigned short, h);
}
__device__ __forceinline__ float bf16tof(unsigned short u) {
    unsigned int xx = ((unsigned int)u) << 16;
    return __builtin_bit_cast(float, xx);
}
__device__ __forceinline__ short8 ld8(const unsigned short* p) {
    return __builtin_bit_cast(short8, *(const uint4v*)p);
}

#define MFMA(a, b, c) __builtin_amdgcn_mfma_f32_16x16x32_bf16((a), (b), (c), 0, 0, 0)

// ---- workspace layout (ushort offsets), 16B-aligned blocks ----
#define W1H_OFF 0        // [64][32]
#define W1L_OFF 2048
#define W2H_OFF 4096     // [64][64]
#define W2L_OFF 8192
#define W3H_OFF 12288    // [16][64], rows 3..15 zero
#define W3L_OFF 13312
#define WS_USHORTS 14336 // 28672 B

__global__ __launch_bounds__(256) void split_weights(
    const float* __restrict__ W1, const float* __restrict__ W2,
    const float* __restrict__ W3, unsigned short* __restrict__ ws)
{
    const int t = blockIdx.x * blockDim.x + threadIdx.x;
    const int stride = gridDim.x * blockDim.x;
    for (int i = t; i < 2048; i += stride) {
        const float v = W1[i];
        const unsigned short hb = bf16rn(v);
        ws[W1H_OFF + i] = hb;
        ws[W1L_OFF + i] = bf16rn(v - bf16tof(hb));
    }
    for (int i = t; i < 4096; i += stride) {
        const float v = W2[i];
        const unsigned short hb = bf16rn(v);
        ws[W2H_OFF + i] = hb;
        ws[W2L_OFF + i] = bf16rn(v - bf16tof(hb));
    }
    for (int i = t; i < 1024; i += stride) {
        const float v = (i < 192) ? W3[i] : 0.0f;   // W3 is [3][64]; pad to 16 rows
        const unsigned short hb = bf16rn(v);
        ws[W3H_OFF + i] = hb;
        ws[W3L_OFF + i] = bf16rn(v - bf16tof(hb));
    }
}

__global__ __launch_bounds__(64, 4) void mh_mfma(
    const float* __restrict__ x,
    const float* __restrict__ tables,
    const unsigned short* __restrict__ wsw,
    const float* __restrict__ b1,
    const float* __restrict__ b2,
    const float* __restrict__ b3,
    float* __restrict__ out,
    ResArr res, int n)
{
    // One 9216 B region, two phases per half:
    //   phase F (encode): sFH [32][40], sFL [32][40]  (5120 B)
    //   phase A (h1/h2):  sAH [32][72], sAL [32][72]  (9216 B, aliases sF)
    __shared__ __align__(16) unsigned short smem[4608];
    unsigned short* const sFH = smem;          // 1280 ushorts
    unsigned short* const sFL = smem + 1280;   // 1280 ushorts
    unsigned short* const sAH = smem;          // 2304 ushorts (aliases sF)
    unsigned short* const sAL = smem + 2304;   // 2304 ushorts

    const int L  = threadIdx.x;
    const int ln = L & 15;
    const int q  = L >> 4;
    const int half_id = L >> 5;     // 0: levels 0-7, 1: levels 8-15
    const int lsub    = L & 31;     // sample-within-half this lane encodes
    const long base = (long)blockIdx.x * 64;

    const float2* __restrict__ tbl2 = reinterpret_cast<const float2*>(tables);

    // biases (per-lane by output column)
    float b1v[4], b2v[4];
    #pragma unroll
    for (int nt = 0; nt < 4; ++nt) { b1v[nt] = b1[nt * 16 + ln]; b2v[nt] = b2[nt * 16 + ln]; }
    const float b3v = (ln < 3) ? b3[ln] : 0.0f;

    const f32x4 zero4 = {0.0f, 0.0f, 0.0f, 0.0f};

    for (int mh = 0; mh < 2; ++mh) {          // 32-sample halves
        // ---- encode this half: 32 samples, 2 lanes/sample (8 levels each) ----
        long s = base + mh * 32 + lsub;
        if (s >= (long)n) s = (long)n - 1;    // clamp loads; stores predicated
        const float2 xv = reinterpret_cast<const float2*>(x)[s];

        #pragma unroll
        for (int j = 0; j < 8; ++j) {
            const int l = half_id * 8 + j;
            // static-indexed select (divergent array index => scratch, rule #20)
            const float r  = half_id ? res.r[j + 8] : res.r[j];
            const float sx = xv.x * r;
            const float sy = xv.y * r;
            const float gx = floorf(sx);
            const float gy = floorf(sy);
            const unsigned ux = (unsigned)(int)gx;
            const unsigned uy = (unsigned)(int)gy;
            const unsigned hy0 = uy * PRIME1;
            const unsigned hy1 = hy0 + PRIME1;
            const unsigned i00 = ( ux       ^ hy0) & TBL_MASK;
            const unsigned i10 = ((ux + 1u) ^ hy0) & TBL_MASK;
            const unsigned i01 = ( ux       ^ hy1) & TBL_MASK;
            const unsigned i11 = ((ux + 1u) ^ hy1) & TBL_MASK;
            const float2* tl = tbl2 + (l << 14);
            const float2 t00 = tl[i00];
            const float2 t10 = tl[i10];
            const float2 t01 = tl[i01];
            const float2 t11 = tl[i11];
            const float wx0 = 1.0f - fabsf(sx - gx);
            const float wx1 = 1.0f - fabsf(sx - (gx + 1.0f));
            const float wy0 = 1.0f - fabsf(sy - gy);
            const float wy1 = 1.0f - fabsf(sy - (gy + 1.0f));
            const float w00 = wx0 * wy0;
            const float w10 = wx1 * wy0;
            const float w01 = wx0 * wy1;
            const float w11 = wx1 * wy1;
            const float f0 = fmaf(w00, t00.x, fmaf(w10, t10.x, fmaf(w01, t01.x, w11 * t11.x)));
            const float f1 = fmaf(w00, t00.y, fmaf(w10, t10.y, fmaf(w01, t01.y, w11 * t11.y)));
            const unsigned short h0 = bf16rn(f0);
            const unsigned short h1e = bf16rn(f1);
            const unsigned short l0 = bf16rn(f0 - bf16tof(h0));
            const unsigned short l1 = bf16rn(f1 - bf16tof(h1e));
            *(unsigned int*)&sFH[lsub * 40 + 2 * l] = (unsigned)h0 | ((unsigned)h1e << 16);
            *(unsigned int*)&sFL[lsub * 40 + 2 * l] = (unsigned)l0 | ((unsigned)l1 << 16);
        }

        // ---- layer-1 A-frags for THIS half (transient, 16 regs) ----
        // Same-wave DS ops retire in order: reads below see the writes above,
        // and the sA writes later may safely alias sF after these reads.
        short8 a1h[2], a1l[2];
        #pragma unroll
        for (int mt = 0; mt < 2; ++mt) {
            const int row = mt * 16 + ln;
            a1h[mt] = ld8(&sFH[row * 40 + q * 8]);
            a1l[mt] = ld8(&sFL[row * 40 + q * 8]);
        }

        // ---------------- layer 1 ----------------
        f32x4 acc1[2][4];
        #pragma unroll
        for (int mt = 0; mt < 2; ++mt)
            #pragma unroll
            for (int nt = 0; nt < 4; ++nt) acc1[mt][nt] = zero4;

        #pragma unroll
        for (int nt = 0; nt < 4; ++nt) {
            const short8 bh = ld8(&wsw[W1H_OFF + (nt * 16 + ln) * 32 + q * 8]);
            const short8 bl = ld8(&wsw[W1L_OFF + (nt * 16 + ln) * 32 + q * 8]);
            #pragma unroll
            for (int mt = 0; mt < 2; ++mt) {
                f32x4 a = acc1[mt][nt];
                a = MFMA(a1l[mt], bh, a);
                a = MFMA(a1h[mt], bl, a);
                a = MFMA(a1h[mt], bh, a);
                acc1[mt][nt] = a;
            }
        }
        // epilogue: bias + relu + split -> sAH/sAL rows 0..31 (aliases sF)
        #pragma unroll
        for (int mt = 0; mt < 2; ++mt)
            #pragma unroll
            for (int nt = 0; nt < 4; ++nt) {
                const int col = nt * 16 + ln;
                #pragma unroll
                for (int r = 0; r < 4; ++r) {
                    float v = fmaxf(acc1[mt][nt][r] + b1v[nt], 0.0f);
                    const unsigned short hb = bf16rn(v);
                    const unsigned short lb = bf16rn(v - bf16tof(hb));
                    const int rl = mt * 16 + q * 4 + r;
                    sAH[rl * 72 + col] = hb;
                    sAL[rl * 72 + col] = lb;
                }
            }

        // ---------------- layer 2 ----------------
        short8 a2h[2][2], a2l[2][2];
        #pragma unroll
        for (int mt = 0; mt < 2; ++mt)
            #pragma unroll
            for (int ks = 0; ks < 2; ++ks) {
                const int row = mt * 16 + ln;
                a2h[mt][ks] = ld8(&sAH[row * 72 + ks * 32 + q * 8]);
                a2l[mt][ks] = ld8(&sAL[row * 72 + ks * 32 + q * 8]);
            }
        f32x4 acc2[2][4];
        #pragma unroll
        for (int mt = 0; mt < 2; ++mt)
            #pragma unroll
            for (int nt = 0; nt < 4; ++nt) acc2[mt][nt] = zero4;

        #pragma unroll
        for (int nt = 0; nt < 4; ++nt)
            #pragma unroll
            for (int ks = 0; ks < 2; ++ks) {
                const short8 bh = ld8(&wsw[W2H_OFF + (nt * 16 + ln) * 64 + ks * 32 + q * 8]);
                const short8 bl = ld8(&wsw[W2L_OFF + (nt * 16 + ln) * 64 + ks * 32 + q * 8]);
                #pragma unroll
                for (int mt = 0; mt < 2; ++mt) {
                    f32x4 a = acc2[mt][nt];
                    a = MFMA(a2l[mt][ks], bh, a);
                    a = MFMA(a2h[mt][ks], bl, a);
                    a = MFMA(a2h[mt][ks], bh, a);
                    acc2[mt][nt] = a;
                }
            }
        // epilogue -> overwrite sAH/sAL (A-frags above already read)
        #pragma unroll
        for (int mt = 0; mt < 2; ++mt)
            #pragma unroll
            for (int nt = 0; nt < 4; ++nt) {
                const int col = nt * 16 + ln;
                #pragma unroll
                for (int r = 0; r < 4; ++r) {
                    float v = fmaxf(acc2[mt][nt][r] + b2v[nt], 0.0f);
                    const unsigned short hb = bf16rn(v);
                    const unsigned short lb = bf16rn(v - bf16tof(hb));
                    const int rl = mt * 16 + q * 4 + r;
                    sAH[rl * 72 + col] = hb;
                    sAL[rl * 72 + col] = lb;
                }
            }

        // ---------------- layer 3 ----------------
        short8 a3h[2][2], a3l[2][2];
        #pragma unroll
        for (int mt = 0; mt < 2; ++mt)
            #pragma unroll
            for (int ks = 0; ks < 2; ++ks) {
                const int row = mt * 16 + ln;
                a3h[mt][ks] = ld8(&sAH[row * 72 + ks * 32 + q * 8]);
                a3l[mt][ks] = ld8(&sAL[row * 72 + ks * 32 + q * 8]);
            }
        f32x4 acc3[2] = {zero4, zero4};
        #pragma unroll
        for (int ks = 0; ks < 2; ++ks) {
            // W3 pre-padded to 16 rows (3..15 zero) -> no divergent mask
            const short8 bh = ld8(&wsw[W3H_OFF + ln * 64 + ks * 32 + q * 8]);
            const short8 bl = ld8(&wsw[W3L_OFF + ln * 64 + ks * 32 + q * 8]);
            #pragma unroll
            for (int mt = 0; mt < 2; ++mt) {
                f32x4 a = acc3[mt];
                a = MFMA(a3l[mt][ks], bh, a);
                a = MFMA(a3h[mt][ks], bl, a);
                a = MFMA(a3h[mt][ks], bh, a);
                acc3[mt] = a;
            }
        }
        // store: C col = ln (channel, <3), rows = samples
        if (ln < 3) {
            #pragma unroll
            for (int mt = 0; mt < 2; ++mt)
                #pragma unroll
                for (int r = 0; r < 4; ++r) {
                    const long sg = base + mh * 32 + mt * 16 + q * 4 + r;
                    if (sg < (long)n) out[sg * 3 + ln] = acc3[mt][r] + b3v;
                }
        }
    }
}

extern "C" void kernel_launch(void* const* d_in, const int* in_sizes, int n_in,
                              void* d_out, int out_size, void* d_ws, size_t ws_size,
                              hipStream_t stream) {
    const float* x      = (const float*)d_in[0];
    const float* tables = (const float*)d_in[1];
    const float* W1     = (const float*)d_in[2];
    const float* b1v    = (const float*)d_in[3];
    const float* W2     = (const float*)d_in[4];
    const float* b2v    = (const float*)d_in[5];
    const float* W3     = (const float*)d_in[6];
    const float* b3v    = (const float*)d_in[7];
    float* out = (float*)d_out;
    unsigned short* wsu = (unsigned short*)d_ws;

    const int n = in_sizes[0] / 2;   // B

    // Replicate numpy's RES computation on the host (glibc libm, float64).
    ResArr ra;
    const double bb = exp((log(512.0) - log(16.0)) / 15.0);
    for (int k = 0; k < 16; ++k) ra.r[k] = (float)floor(16.0 * pow(bb, (double)k));

    // Prepass: hi/lo bf16 weight split into workspace (stream-ordered).
    hipLaunchKernelGGL(split_weights, dim3(8), dim3(256), 0, stream, W1, W2, W3, wsu);

    dim3 grid((n + 63) / 64), block(64);
    hipLaunchKernelGGL(mh_mfma, grid, block, 0, stream,
                       x, tables, wsu, b1v, b2v, b3v, out, ra, n);
}

// Round 6
// 259.324 us; speedup vs baseline: 1.5701x; 1.5701x over previous
//
#include <hip/hip_runtime.h>
#include <hip/hip_bf16.h>
#include <math.h>

// MultiHash R12: buy occupancy with LDS ONLY — zero register cost.
// Session table: R6 (8 blocks/CU, no reg cap) 187us > R8 (12 blocks/CU,
// (64,3) cap + 32-reg preload) 226us -> the reg cap throttles gather ILP;
// occupancy must come from LDS, never from launch_bounds caps (and (64,4)
// spills, 3x confirmed).
// Change vs R6: sF split into per-half blocks [H0|L0] [gap] [H1|L1];
// sA (9216 B) aliases H0/L0+gap at [0,9216)B and never touches H1/L1 at
// [9216,14336)B. Sequencing: encode all 64 rows -> half-0 a1 read from
// H0/L0 -> half-0 MLP (sA clobbers [0,9216) only) -> half-1 a1 read from
// untouched H1/L1 -> half-1 MLP. Same-wave DS ops retire in order; single
// wave per block -> no barriers. LDS 19456 -> 14336 B = 11 blocks/CU.
// Also kept from R8 (the one clearly-good change): weight-split prepass
// into d_ws -> B-frags are plain 16B global loads, no per-wave splitW.
// Encoding math / fragment layouts / epilogues: R6-validated
// (absmax 1.49e-8 vs 8.9e-8 threshold).

#define TBL_MASK 16383u
#define PRIME1   2654435761u

typedef __attribute__((ext_vector_type(8))) short short8;
typedef __attribute__((ext_vector_type(4))) float f32x4;
typedef __attribute__((ext_vector_type(4))) unsigned int uint4v;

struct ResArr { float r[16]; };

__device__ __forceinline__ unsigned short bf16rn(float f) {
    __hip_bfloat16 h = __float2bfloat16(f);   // RNE
    return __builtin_bit_cast(unsigned short, h);
}
__device__ __forceinline__ float bf16tof(unsigned short u) {
    unsigned int xx = ((unsigned int)u) << 16;
    return __builtin_bit_cast(float, xx);
}
__device__ __forceinline__ short8 ld8(const unsigned short* p) {
    return __builtin_bit_cast(short8, *(const uint4v*)p);
}

#define MFMA(a, b, c) __builtin_amdgcn_mfma_f32_16x16x32_bf16((a), (b), (c), 0, 0, 0)

// ---- workspace layout (ushort offsets), 16B-aligned blocks ----
#define W1H_OFF 0        // [64][32]
#define W1L_OFF 2048
#define W2H_OFF 4096     // [64][64]
#define W2L_OFF 8192
#define W3H_OFF 12288    // [16][64], rows 3..15 zero
#define W3L_OFF 13312
#define WS_USHORTS 14336 // 28672 B

__global__ __launch_bounds__(256) void split_weights(
    const float* __restrict__ W1, const float* __restrict__ W2,
    const float* __restrict__ W3, unsigned short* __restrict__ ws)
{
    const int t = blockIdx.x * blockDim.x + threadIdx.x;
    const int stride = gridDim.x * blockDim.x;
    for (int i = t; i < 2048; i += stride) {
        const float v = W1[i];
        const unsigned short hb = bf16rn(v);
        ws[W1H_OFF + i] = hb;
        ws[W1L_OFF + i] = bf16rn(v - bf16tof(hb));
    }
    for (int i = t; i < 4096; i += stride) {
        const float v = W2[i];
        const unsigned short hb = bf16rn(v);
        ws[W2H_OFF + i] = hb;
        ws[W2L_OFF + i] = bf16rn(v - bf16tof(hb));
    }
    for (int i = t; i < 1024; i += stride) {
        const float v = (i < 192) ? W3[i] : 0.0f;   // W3 is [3][64]; pad to 16 rows
        const unsigned short hb = bf16rn(v);
        ws[W3H_OFF + i] = hb;
        ws[W3L_OFF + i] = bf16rn(v - bf16tof(hb));
    }
}

__global__ __launch_bounds__(64) void mh_mfma(
    const float* __restrict__ x,
    const float* __restrict__ tables,
    const unsigned short* __restrict__ wsw,
    const float* __restrict__ b1,
    const float* __restrict__ b2,
    const float* __restrict__ b3,
    float* __restrict__ out,
    ResArr res, int n)
{
    // smem layout (ushort offsets), 14336 B total:
    //   H0  [   0,1280)  feat hi, rows  0-31, stride 40
    //   L0  [1280,2560)  feat lo, rows  0-31
    //   gap [2560,4608)  (sA only)
    //   H1  [4608,5888)  feat hi, rows 32-63
    //   L1  [5888,7168)  feat lo, rows 32-63
    //   sAH [   0,2304)  h1/h2 hi, 32 rows x 72   (aliases H0/L0/gap)
    //   sAL [2304,4608)  h1/h2 lo                 (ends exactly at H1)
    __shared__ __align__(16) unsigned short smem[7168];
    unsigned short* const sAH = smem;
    unsigned short* const sAL = smem + 2304;

    const int L  = threadIdx.x;
    const int ln = L & 15;
    const int q  = L >> 4;
    const long base = (long)blockIdx.x * 64;
    long s = base + L;
    if (s >= (long)n) s = (long)n - 1;   // clamp loads; stores predicated below

    const float2 xv = reinterpret_cast<const float2*>(x)[s];
    const float2* __restrict__ tbl2 = reinterpret_cast<const float2*>(tables);

    // per-lane feat write bases: rows 0-31 -> H0/L0, rows 32-63 -> H1/L1
    const int fhb = (L >> 5) * 3328 + L * 40;   // hi base (ushort offset)
    // (L>=32: 3328 + L*40 = 4608 + (L-32)*40)

    // ---- encoding: identical math to R1/R6 (validated) ----
    #pragma unroll 4
    for (int l = 0; l < 16; ++l) {
        const float r  = res.r[l];
        const float sx = xv.x * r;
        const float sy = xv.y * r;
        const float gx = floorf(sx);
        const float gy = floorf(sy);
        const unsigned ux = (unsigned)(int)gx;
        const unsigned uy = (unsigned)(int)gy;
        const unsigned hy0 = uy * PRIME1;
        const unsigned hy1 = hy0 + PRIME1;
        const unsigned i00 = ( ux       ^ hy0) & TBL_MASK;
        const unsigned i10 = ((ux + 1u) ^ hy0) & TBL_MASK;
        const unsigned i01 = ( ux       ^ hy1) & TBL_MASK;
        const unsigned i11 = ((ux + 1u) ^ hy1) & TBL_MASK;
        const float2* tl = tbl2 + (l << 14);
        const float2 t00 = tl[i00];
        const float2 t10 = tl[i10];
        const float2 t01 = tl[i01];
        const float2 t11 = tl[i11];
        const float wx0 = 1.0f - fabsf(sx - gx);
        const float wx1 = 1.0f - fabsf(sx - (gx + 1.0f));
        const float wy0 = 1.0f - fabsf(sy - gy);
        const float wy1 = 1.0f - fabsf(sy - (gy + 1.0f));
        const float w00 = wx0 * wy0;
        const float w10 = wx1 * wy0;
        const float w01 = wx0 * wy1;
        const float w11 = wx1 * wy1;
        const float f0 = fmaf(w00, t00.x, fmaf(w10, t10.x, fmaf(w01, t01.x, w11 * t11.x)));
        const float f1 = fmaf(w00, t00.y, fmaf(w10, t10.y, fmaf(w01, t01.y, w11 * t11.y)));
        const unsigned short h0 = bf16rn(f0);
        const unsigned short h1e = bf16rn(f1);
        const unsigned short l0 = bf16rn(f0 - bf16tof(h0));
        const unsigned short l1 = bf16rn(f1 - bf16tof(h1e));
        *(unsigned int*)&smem[fhb + 2 * l]        = (unsigned)h0 | ((unsigned)h1e << 16);
        *(unsigned int*)&smem[fhb + 1280 + 2 * l] = (unsigned)l0 | ((unsigned)l1 << 16);
    }

    // biases (per-lane by output column)
    float b1v[4], b2v[4];
    #pragma unroll
    for (int nt = 0; nt < 4; ++nt) { b1v[nt] = b1[nt * 16 + ln]; b2v[nt] = b2[nt * 16 + ln]; }
    const float b3v = (ln < 3) ? b3[ln] : 0.0f;

    const f32x4 zero4 = {0.0f, 0.0f, 0.0f, 0.0f};

    for (int mh = 0; mh < 2; ++mh) {          // 32-sample halves
        // ---- a1 frags for THIS half (transient; half-1's region untouched
        //      by half-0's sA writes, which stay < ushort 4608) ----
        const int fb = mh ? 4608 : 0;
        short8 a1h[2], a1l[2];
        #pragma unroll
        for (int mt = 0; mt < 2; ++mt) {
            const int row = mt * 16 + ln;
            a1h[mt] = ld8(&smem[fb + row * 40 + q * 8]);
            a1l[mt] = ld8(&smem[fb + 1280 + row * 40 + q * 8]);
        }

        // ---------------- layer 1 ----------------
        f32x4 acc1[2][4];
        #pragma unroll
        for (int mt = 0; mt < 2; ++mt)
            #pragma unroll
            for (int nt = 0; nt < 4; ++nt) acc1[mt][nt] = zero4;

        #pragma unroll
        for (int nt = 0; nt < 4; ++nt) {
            const short8 bh = ld8(&wsw[W1H_OFF + (nt * 16 + ln) * 32 + q * 8]);
            const short8 bl = ld8(&wsw[W1L_OFF + (nt * 16 + ln) * 32 + q * 8]);
            #pragma unroll
            for (int mt = 0; mt < 2; ++mt) {
                f32x4 a = acc1[mt][nt];
                a = MFMA(a1l[mt], bh, a);
                a = MFMA(a1h[mt], bl, a);
                a = MFMA(a1h[mt], bh, a);
                acc1[mt][nt] = a;
            }
        }
        // epilogue: bias + relu + split -> sAH/sAL (a1 of this half already
        // read; writes stay below ushort 4608 so half-1 feat is safe)
        #pragma unroll
        for (int mt = 0; mt < 2; ++mt)
            #pragma unroll
            for (int nt = 0; nt < 4; ++nt) {
                const int col = nt * 16 + ln;
                #pragma unroll
                for (int r = 0; r < 4; ++r) {
                    float v = fmaxf(acc1[mt][nt][r] + b1v[nt], 0.0f);
                    const unsigned short hb = bf16rn(v);
                    const unsigned short lb = bf16rn(v - bf16tof(hb));
                    const int rl = mt * 16 + q * 4 + r;
                    sAH[rl * 72 + col] = hb;
                    sAL[rl * 72 + col] = lb;
                }
            }

        // ---------------- layer 2 ----------------
        short8 a2h[2][2], a2l[2][2];
        #pragma unroll
        for (int mt = 0; mt < 2; ++mt)
            #pragma unroll
            for (int ks = 0; ks < 2; ++ks) {
                const int row = mt * 16 + ln;
                a2h[mt][ks] = ld8(&sAH[row * 72 + ks * 32 + q * 8]);
                a2l[mt][ks] = ld8(&sAL[row * 72 + ks * 32 + q * 8]);
            }
        f32x4 acc2[2][4];
        #pragma unroll
        for (int mt = 0; mt < 2; ++mt)
            #pragma unroll
            for (int nt = 0; nt < 4; ++nt) acc2[mt][nt] = zero4;

        #pragma unroll
        for (int nt = 0; nt < 4; ++nt)
            #pragma unroll
            for (int ks = 0; ks < 2; ++ks) {
                const short8 bh = ld8(&wsw[W2H_OFF + (nt * 16 + ln) * 64 + ks * 32 + q * 8]);
                const short8 bl = ld8(&wsw[W2L_OFF + (nt * 16 + ln) * 64 + ks * 32 + q * 8]);
                #pragma unroll
                for (int mt = 0; mt < 2; ++mt) {
                    f32x4 a = acc2[mt][nt];
                    a = MFMA(a2l[mt][ks], bh, a);
                    a = MFMA(a2h[mt][ks], bl, a);
                    a = MFMA(a2h[mt][ks], bh, a);
                    acc2[mt][nt] = a;
                }
            }
        // epilogue -> overwrite sAH/sAL (A-frags above already read)
        #pragma unroll
        for (int mt = 0; mt < 2; ++mt)
            #pragma unroll
            for (int nt = 0; nt < 4; ++nt) {
                const int col = nt * 16 + ln;
                #pragma unroll
                for (int r = 0; r < 4; ++r) {
                    float v = fmaxf(acc2[mt][nt][r] + b2v[nt], 0.0f);
                    const unsigned short hb = bf16rn(v);
                    const unsigned short lb = bf16rn(v - bf16tof(hb));
                    const int rl = mt * 16 + q * 4 + r;
                    sAH[rl * 72 + col] = hb;
                    sAL[rl * 72 + col] = lb;
                }
            }

        // ---------------- layer 3 ----------------
        short8 a3h[2][2], a3l[2][2];
        #pragma unroll
        for (int mt = 0; mt < 2; ++mt)
            #pragma unroll
            for (int ks = 0; ks < 2; ++ks) {
                const int row = mt * 16 + ln;
                a3h[mt][ks] = ld8(&sAH[row * 72 + ks * 32 + q * 8]);
                a3l[mt][ks] = ld8(&sAL[row * 72 + ks * 32 + q * 8]);
            }
        f32x4 acc3[2] = {zero4, zero4};
        #pragma unroll
        for (int ks = 0; ks < 2; ++ks) {
            // W3 pre-padded to 16 rows (3..15 zero) -> no divergent mask
            const short8 bh = ld8(&wsw[W3H_OFF + ln * 64 + ks * 32 + q * 8]);
            const short8 bl = ld8(&wsw[W3L_OFF + ln * 64 + ks * 32 + q * 8]);
            #pragma unroll
            for (int mt = 0; mt < 2; ++mt) {
                f32x4 a = acc3[mt];
                a = MFMA(a3l[mt][ks], bh, a);
                a = MFMA(a3h[mt][ks], bl, a);
                a = MFMA(a3h[mt][ks], bh, a);
                acc3[mt] = a;
            }
        }
        // store: C col = ln (channel, <3), rows = samples
        if (ln < 3) {
            #pragma unroll
            for (int mt = 0; mt < 2; ++mt)
                #pragma unroll
                for (int r = 0; r < 4; ++r) {
                    const long sg = base + mh * 32 + mt * 16 + q * 4 + r;
                    if (sg < (long)n) out[sg * 3 + ln] = acc3[mt][r] + b3v;
                }
        }
    }
}

extern "C" void kernel_launch(void* const* d_in, const int* in_sizes, int n_in,
                              void* d_out, int out_size, void* d_ws, size_t ws_size,
                              hipStream_t stream) {
    const float* x      = (const float*)d_in[0];
    const float* tables = (const float*)d_in[1];
    const float* W1     = (const float*)d_in[2];
    const float* b1v    = (const float*)d_in[3];
    const float* W2     = (const float*)d_in[4];
    const float* b2v    = (const float*)d_in[5];
    const float* W3     = (const float*)d_in[6];
    const float* b3v    = (const float*)d_in[7];
    float* out = (float*)d_out;
    unsigned short* wsu = (unsigned short*)d_ws;

    const int n = in_sizes[0] / 2;   // B

    // Replicate numpy's RES computation on the host (glibc libm, float64).
    ResArr ra;
    const double bb = exp((log(512.0) - log(16.0)) / 15.0);
    for (int k = 0; k < 16; ++k) ra.r[k] = (float)floor(16.0 * pow(bb, (double)k));

    // Prepass: hi/lo bf16 weight split into workspace (stream-ordered).
    hipLaunchKernelGGL(split_weights, dim3(8), dim3(256), 0, stream, W1, W2, W3, wsu);

    dim3 grid((n + 63) / 64), block(64);
    hipLaunchKernelGGL(mh_mfma, grid, block, 0, stream,
                       x, tables, wsu, b1v, b2v, b3v, out, ra, n);
}